// Round 1
// baseline (13.276 us; speedup 1.0000x reference)
//
#include <hip/hip_runtime.h>

#define DT_STEP 0.01f

constexpr int HW  = 512 * 512;   // 262144
constexpr int HW4 = HW / 4;      // 65536 float4's per plane

// ---------------------------------------------------------------------------
// sum across each 16-lane group of the wave
__device__ inline float rsum16(float x) {
    x += __shfl_xor(x, 1);
    x += __shfl_xor(x, 2);
    x += __shfl_xor(x, 4);
    x += __shfl_xor(x, 8);
    return x;
}

// ---------------------------------------------------------------------------
// Prepass: collapse all weight tensors into 40 polynomial coefficients.
// coef[0..11]  : quadratic coeffs (A,B,C) for grads i=0..3   (in s)
// coef[12..19] : cubic coeffs (c3,c2,c1,c0) for diff i=0..1  (in s)
// coef[20..39] : bivariate-cubic coeffs (10 each) for phi_src o=0..1
//                order: u3, u2v, uv2, v3, u2, uv, v2, u, v, 1
__global__ void percnn_coef_kernel(
        const float* __restrict__ Wc_in,  const float* __restrict__ bc_in,
        const float* __restrict__ Wc_out, const float* __restrict__ bc_out,
        const float* __restrict__ Wd_in,  const float* __restrict__ bd_in,
        const float* __restrict__ Wd_out, const float* __restrict__ bd_out,
        const float* __restrict__ Ws_in,  const float* __restrict__ bs_in,
        const float* __restrict__ Ws_out, const float* __restrict__ bs_out,
        float* __restrict__ coef) {
    const int lane = threadIdx.x;      // 0..63
    const int c    = lane & 15;

    // ---- conv gradients: 4 quadratics, all 64 lanes (i = lane>>4) ----
    {
        const int i = lane >> 4;
        float w0 = Wc_in[(i * 2 + 0) * 16 + c], b0 = bc_in[(i * 2 + 0) * 16 + c];
        float w1 = Wc_in[(i * 2 + 1) * 16 + c], b1 = bc_in[(i * 2 + 1) * 16 + c];
        float wo = Wc_out[i * 16 + c];
        float pa = rsum16(wo * w0 * w1);
        float pb = rsum16(wo * (w0 * b1 + b0 * w1));
        float pc = rsum16(wo * b0 * b1);
        if (c == 0) {
            coef[i * 3 + 0] = pa;
            coef[i * 3 + 1] = pb;
            coef[i * 3 + 2] = pc + bc_out[i];
        }
    }

    // ---- diffusion: 2 cubics, lanes 0..31 (i = lane>>4) ----
    if (lane < 32) {
        const int i = lane >> 4;
        float a1 = Wd_in[(i * 3 + 0) * 16 + c], b1 = bd_in[(i * 3 + 0) * 16 + c];
        float a2 = Wd_in[(i * 3 + 1) * 16 + c], b2 = bd_in[(i * 3 + 1) * 16 + c];
        float a3 = Wd_in[(i * 3 + 2) * 16 + c], b3 = bd_in[(i * 3 + 2) * 16 + c];
        float wo = Wd_out[i * 16 + c];
        float c3 = rsum16(wo * (a1 * a2 * a3));
        float c2 = rsum16(wo * (a1 * a2 * b3 + a1 * b2 * a3 + b1 * a2 * a3));
        float c1 = rsum16(wo * (a1 * b2 * b3 + b1 * a2 * b3 + b1 * b2 * a3));
        float c0 = rsum16(wo * (b1 * b2 * b3));
        if (c == 0) {
            coef[12 + i * 4 + 0] = c3;
            coef[12 + i * 4 + 1] = c2;
            coef[12 + i * 4 + 2] = c1;
            coef[12 + i * 4 + 3] = c0 + bd_out[i];
        }
    }

    // ---- source: 2 bivariate cubics, lanes 0..31 (o = lane>>4) ----
    if (lane < 32) {
        const int o = lane >> 4;
        float p1 = Ws_in[(0 * 16 + c) * 2 + 0], q1 = Ws_in[(0 * 16 + c) * 2 + 1], r1 = bs_in[0 * 16 + c];
        float p2 = Ws_in[(1 * 16 + c) * 2 + 0], q2 = Ws_in[(1 * 16 + c) * 2 + 1], r2 = bs_in[1 * 16 + c];
        float p3 = Ws_in[(2 * 16 + c) * 2 + 0], q3 = Ws_in[(2 * 16 + c) * 2 + 1], r3 = bs_in[2 * 16 + c];
        float wo = Ws_out[o * 16 + c];
        float t[10];
        t[0] = p1 * p2 * p3;                                                              // u^3
        t[1] = p1 * p2 * q3 + p1 * q2 * p3 + q1 * p2 * p3;                                // u^2 v
        t[2] = p1 * q2 * q3 + q1 * p2 * q3 + q1 * q2 * p3;                                // u v^2
        t[3] = q1 * q2 * q3;                                                              // v^3
        t[4] = p1 * p2 * r3 + p1 * r2 * p3 + r1 * p2 * p3;                                // u^2
        t[5] = p1 * q2 * r3 + p1 * r2 * q3 + q1 * p2 * r3
             + q1 * r2 * p3 + r1 * p2 * q3 + r1 * q2 * p3;                                // u v
        t[6] = q1 * q2 * r3 + q1 * r2 * q3 + r1 * q2 * q3;                                // v^2
        t[7] = p1 * r2 * r3 + r1 * p2 * r3 + r1 * r2 * p3;                                // u
        t[8] = q1 * r2 * r3 + r1 * q2 * r3 + r1 * r2 * q3;                                // v
        t[9] = r1 * r2 * r3;                                                              // 1
#pragma unroll
        for (int j = 0; j < 10; ++j) {
            float s = rsum16(wo * t[j]);
            if (c == 0) coef[20 + o * 10 + j] = s + ((j == 9) ? bs_out[o] : 0.0f);
        }
    }
}

// ---------------------------------------------------------------------------
// Main elementwise kernel: out[b,ch,h,w] from u,v = x[b, T-1, {0,1}, h, w]
__global__ __launch_bounds__(256) void percnn_step_kernel(
        const float* __restrict__ x, const float* __restrict__ nu,
        const float* __restrict__ coef, float* __restrict__ out) {
    const int g = blockIdx.x * 256 + threadIdx.x;   // 0 .. 4*HW4-1
    const int b = g >> 16;                          // HW4 == 65536
    const int p = g & (HW4 - 1);

    // coefficients (uniform; L1-resident)
    float A[4], Bq[4], Cq[4];
#pragma unroll
    for (int i = 0; i < 4; ++i) {
        A[i]  = coef[i * 3 + 0];
        Bq[i] = coef[i * 3 + 1];
        Cq[i] = coef[i * 3 + 2];
    }
    float D[2][4];
#pragma unroll
    for (int i = 0; i < 2; ++i)
#pragma unroll
        for (int j = 0; j < 4; ++j) D[i][j] = coef[12 + i * 4 + j];
    float S[2][10];
#pragma unroll
    for (int o = 0; o < 2; ++o)
#pragma unroll
        for (int j = 0; j < 10; ++j) S[o][j] = coef[20 + o * 10 + j];

    const float nub = nu[b];

    // x[b, 7, ch] plane base (in float4 units)
    const float4* up = (const float4*)x + (size_t)((b * 8 + 7) * 2 + 0) * HW4 + p;
    const float4* vp = (const float4*)x + (size_t)((b * 8 + 7) * 2 + 1) * HW4 + p;
    float4 u4 = *up;
    float4 v4 = *vp;

    float4 o0, o1;
    const float* uu = (const float*)&u4;
    const float* vv = (const float*)&v4;
    float* r0 = (float*)&o0;
    float* r1 = (float*)&o1;

#pragma unroll
    for (int e = 0; e < 4; ++e) {
        const float u = uu[e], v = vv[e];
        // quadratic gradient surrogates
        float gxu = (A[0] * u + Bq[0]) * u + Cq[0];
        float gyu = (A[1] * u + Bq[1]) * u + Cq[1];
        float gxv = (A[2] * v + Bq[2]) * v + Cq[2];
        float gyv = (A[3] * v + Bq[3]) * v + Cq[3];
        float conv0 = u * gxu + v * gyu;
        float conv1 = u * gxv + v * gyv;
        // cubic diffusion surrogates
        float d0 = ((D[0][0] * u + D[0][1]) * u + D[0][2]) * u + D[0][3];
        float d1 = ((D[1][0] * v + D[1][1]) * v + D[1][2]) * v + D[1][3];
        // bivariate cubic source
        float u2 = u * u, v2 = v * v, uv = u * v;
        float s0 = u2 * (S[0][0] * u + S[0][1] * v + S[0][4])
                 + v2 * (S[0][2] * u + S[0][3] * v + S[0][6])
                 + uv * S[0][5] + S[0][7] * u + S[0][8] * v + S[0][9];
        float s1 = u2 * (S[1][0] * u + S[1][1] * v + S[1][4])
                 + v2 * (S[1][2] * u + S[1][3] * v + S[1][6])
                 + uv * S[1][5] + S[1][7] * u + S[1][8] * v + S[1][9];
        r0[e] = u + (nub * d0 - conv0 + s0) * DT_STEP;
        r1[e] = v + (nub * d1 - conv1 + s1) * DT_STEP;
    }

    float4* out0 = (float4*)out + (size_t)(b * 2 + 0) * HW4 + p;
    float4* out1 = (float4*)out + (size_t)(b * 2 + 1) * HW4 + p;
    *out0 = o0;
    *out1 = o1;
}

// ---------------------------------------------------------------------------
extern "C" void kernel_launch(void* const* d_in, const int* in_sizes, int n_in,
                              void* d_out, int out_size, void* d_ws, size_t ws_size,
                              hipStream_t stream) {
    const float* x      = (const float*)d_in[0];
    const float* nu     = (const float*)d_in[1];
    const float* Wc_in  = (const float*)d_in[2];
    const float* bc_in  = (const float*)d_in[3];
    const float* Wc_out = (const float*)d_in[4];
    const float* bc_out = (const float*)d_in[5];
    const float* Wd_in  = (const float*)d_in[6];
    const float* bd_in  = (const float*)d_in[7];
    const float* Wd_out = (const float*)d_in[8];
    const float* bd_out = (const float*)d_in[9];
    const float* Ws_in  = (const float*)d_in[10];
    const float* bs_in  = (const float*)d_in[11];
    const float* Ws_out = (const float*)d_in[12];
    const float* bs_out = (const float*)d_in[13];

    float* coef = (float*)d_ws;   // 40 floats

    percnn_coef_kernel<<<1, 64, 0, stream>>>(
        Wc_in, bc_in, Wc_out, bc_out, Wd_in, bd_in, Wd_out, bd_out,
        Ws_in, bs_in, Ws_out, bs_out, coef);

    const int total = 4 * HW4;            // 262144 float4 work items
    percnn_step_kernel<<<total / 256, 256, 0, stream>>>(
        x, nu, coef, (float*)d_out);
}

// Round 2
// 12.946 us; speedup vs baseline: 1.0255x; 1.0255x over previous
//
#include <hip/hip_runtime.h>

#define DT_STEP 0.01f

constexpr int HW  = 512 * 512;   // 262144
constexpr int HW4 = HW / 4;      // 65536 float4's per plane

// sum across each 16-lane group of the wave
__device__ inline float rsum16(float x) {
    x += __shfl_xor(x, 1);
    x += __shfl_xor(x, 2);
    x += __shfl_xor(x, 4);
    x += __shfl_xor(x, 8);
    return x;
}

// ---------------------------------------------------------------------------
// Fused kernel. Phase 1 (wave 0): collapse all weight tensors into 40
// polynomial coefficients in LDS (DT pre-folded). Phase 2: elementwise map.
//
// sc[0..11]  : quadratic coeffs (A,B,C)*DT for grads i=0..3     (in s)
// sc[12..19] : cubic coeffs (c3..c0)*DT    for diff i=0..1      (in s)
// sc[20..39] : bivariate-cubic coeffs*DT (10 each) for src o=0..1
//              order: u3, u2v, uv2, v3, u2, uv, v2, u, v, 1
__global__ __launch_bounds__(256) void percnn_fused_kernel(
        const float* __restrict__ x, const float* __restrict__ nu,
        const float* __restrict__ Wc_in,  const float* __restrict__ bc_in,
        const float* __restrict__ Wc_out, const float* __restrict__ bc_out,
        const float* __restrict__ Wd_in,  const float* __restrict__ bd_in,
        const float* __restrict__ Wd_out, const float* __restrict__ bd_out,
        const float* __restrict__ Ws_in,  const float* __restrict__ bs_in,
        const float* __restrict__ Ws_out, const float* __restrict__ bs_out,
        float* __restrict__ out) {
    __shared__ float sc[40];

    const int g = blockIdx.x * 256 + threadIdx.x;   // 0 .. 4*HW4-1
    const int b = g >> 16;                          // HW4 == 65536
    const int p = g & (HW4 - 1);

    // ---- issue the HBM loads FIRST so they overlap the coef phase ----
    const float4* up = (const float4*)x + (size_t)((b * 8 + 7) * 2 + 0) * HW4 + p;
    const float4* vp = (const float4*)x + (size_t)((b * 8 + 7) * 2 + 1) * HW4 + p;
    float4 u4 = *up;
    float4 v4 = *vp;
    const float nub = nu[b];

    // ---- phase 1: wave 0 computes the 40 coefficients into LDS ----
    if (threadIdx.x < 64) {
        const int lane = threadIdx.x;
        const int c    = lane & 15;

        { // conv gradients: 4 quadratics (i = lane>>4)
            const int i = lane >> 4;
            float w0 = Wc_in[(i * 2 + 0) * 16 + c], b0 = bc_in[(i * 2 + 0) * 16 + c];
            float w1 = Wc_in[(i * 2 + 1) * 16 + c], b1 = bc_in[(i * 2 + 1) * 16 + c];
            float wo = Wc_out[i * 16 + c];
            float pa = rsum16(wo * w0 * w1);
            float pb = rsum16(wo * (w0 * b1 + b0 * w1));
            float pc = rsum16(wo * b0 * b1);
            if (c == 0) {
                sc[i * 3 + 0] = pa * DT_STEP;
                sc[i * 3 + 1] = pb * DT_STEP;
                sc[i * 3 + 2] = (pc + bc_out[i]) * DT_STEP;
            }
        }
        if (lane < 32) { // diffusion: 2 cubics (i = lane>>4)
            const int i = lane >> 4;
            float a1 = Wd_in[(i * 3 + 0) * 16 + c], b1 = bd_in[(i * 3 + 0) * 16 + c];
            float a2 = Wd_in[(i * 3 + 1) * 16 + c], b2 = bd_in[(i * 3 + 1) * 16 + c];
            float a3 = Wd_in[(i * 3 + 2) * 16 + c], b3 = bd_in[(i * 3 + 2) * 16 + c];
            float wo = Wd_out[i * 16 + c];
            float c3 = rsum16(wo * (a1 * a2 * a3));
            float c2 = rsum16(wo * (a1 * a2 * b3 + a1 * b2 * a3 + b1 * a2 * a3));
            float c1 = rsum16(wo * (a1 * b2 * b3 + b1 * a2 * b3 + b1 * b2 * a3));
            float c0 = rsum16(wo * (b1 * b2 * b3));
            if (c == 0) {
                sc[12 + i * 4 + 0] = c3 * DT_STEP;
                sc[12 + i * 4 + 1] = c2 * DT_STEP;
                sc[12 + i * 4 + 2] = c1 * DT_STEP;
                sc[12 + i * 4 + 3] = (c0 + bd_out[i]) * DT_STEP;
            }
        }
        if (lane < 32) { // source: 2 bivariate cubics (o = lane>>4)
            const int o = lane >> 4;
            float p1 = Ws_in[(0 * 16 + c) * 2 + 0], q1 = Ws_in[(0 * 16 + c) * 2 + 1], r1 = bs_in[0 * 16 + c];
            float p2 = Ws_in[(1 * 16 + c) * 2 + 0], q2 = Ws_in[(1 * 16 + c) * 2 + 1], r2 = bs_in[1 * 16 + c];
            float p3 = Ws_in[(2 * 16 + c) * 2 + 0], q3 = Ws_in[(2 * 16 + c) * 2 + 1], r3 = bs_in[2 * 16 + c];
            float wo = Ws_out[o * 16 + c];
            float t[10];
            t[0] = p1 * p2 * p3;
            t[1] = p1 * p2 * q3 + p1 * q2 * p3 + q1 * p2 * p3;
            t[2] = p1 * q2 * q3 + q1 * p2 * q3 + q1 * q2 * p3;
            t[3] = q1 * q2 * q3;
            t[4] = p1 * p2 * r3 + p1 * r2 * p3 + r1 * p2 * p3;
            t[5] = p1 * q2 * r3 + p1 * r2 * q3 + q1 * p2 * r3
                 + q1 * r2 * p3 + r1 * p2 * q3 + r1 * q2 * p3;
            t[6] = q1 * q2 * r3 + q1 * r2 * q3 + r1 * q2 * q3;
            t[7] = p1 * r2 * r3 + r1 * p2 * r3 + r1 * r2 * p3;
            t[8] = q1 * r2 * r3 + r1 * q2 * r3 + r1 * r2 * q3;
            t[9] = r1 * r2 * r3;
#pragma unroll
            for (int j = 0; j < 10; ++j) {
                float s = rsum16(wo * t[j]);
                if (c == 0) sc[20 + o * 10 + j] = (s + ((j == 9) ? bs_out[o] : 0.0f)) * DT_STEP;
            }
        }
    }
    __syncthreads();

    // ---- phase 2: elementwise polynomial evaluation ----
    float A[4], Bq[4], Cq[4];
#pragma unroll
    for (int i = 0; i < 4; ++i) {
        A[i]  = sc[i * 3 + 0];
        Bq[i] = sc[i * 3 + 1];
        Cq[i] = sc[i * 3 + 2];
    }
    float D[2][4];
#pragma unroll
    for (int i = 0; i < 2; ++i)
#pragma unroll
        for (int j = 0; j < 4; ++j) D[i][j] = sc[12 + i * 4 + j];
    float S[2][10];
#pragma unroll
    for (int o = 0; o < 2; ++o)
#pragma unroll
        for (int j = 0; j < 10; ++j) S[o][j] = sc[20 + o * 10 + j];

    float4 o0, o1;
    const float* uu = (const float*)&u4;
    const float* vv = (const float*)&v4;
    float* r0 = (float*)&o0;
    float* r1 = (float*)&o1;

#pragma unroll
    for (int e = 0; e < 4; ++e) {
        const float u = uu[e], v = vv[e];
        // quadratic gradient surrogates (DT folded)
        float gxu = (A[0] * u + Bq[0]) * u + Cq[0];
        float gyu = (A[1] * u + Bq[1]) * u + Cq[1];
        float gxv = (A[2] * v + Bq[2]) * v + Cq[2];
        float gyv = (A[3] * v + Bq[3]) * v + Cq[3];
        float conv0 = u * gxu + v * gyu;
        float conv1 = u * gxv + v * gyv;
        // cubic diffusion surrogates (DT folded)
        float d0 = ((D[0][0] * u + D[0][1]) * u + D[0][2]) * u + D[0][3];
        float d1 = ((D[1][0] * v + D[1][1]) * v + D[1][2]) * v + D[1][3];
        // bivariate cubic source (DT folded)
        float u2 = u * u, v2 = v * v, uv = u * v;
        float s0 = u2 * (S[0][0] * u + S[0][1] * v + S[0][4])
                 + v2 * (S[0][2] * u + S[0][3] * v + S[0][6])
                 + uv * S[0][5] + S[0][7] * u + S[0][8] * v + S[0][9];
        float s1 = u2 * (S[1][0] * u + S[1][1] * v + S[1][4])
                 + v2 * (S[1][2] * u + S[1][3] * v + S[1][6])
                 + uv * S[1][5] + S[1][7] * u + S[1][8] * v + S[1][9];
        r0[e] = u + nub * d0 - conv0 + s0;
        r1[e] = v + nub * d1 - conv1 + s1;
    }

    float4* out0 = (float4*)out + (size_t)(b * 2 + 0) * HW4 + p;
    float4* out1 = (float4*)out + (size_t)(b * 2 + 1) * HW4 + p;
    *out0 = o0;
    *out1 = o1;
}

// ---------------------------------------------------------------------------
extern "C" void kernel_launch(void* const* d_in, const int* in_sizes, int n_in,
                              void* d_out, int out_size, void* d_ws, size_t ws_size,
                              hipStream_t stream) {
    const float* x      = (const float*)d_in[0];
    const float* nu     = (const float*)d_in[1];
    const float* Wc_in  = (const float*)d_in[2];
    const float* bc_in  = (const float*)d_in[3];
    const float* Wc_out = (const float*)d_in[4];
    const float* bc_out = (const float*)d_in[5];
    const float* Wd_in  = (const float*)d_in[6];
    const float* bd_in  = (const float*)d_in[7];
    const float* Wd_out = (const float*)d_in[8];
    const float* bd_out = (const float*)d_in[9];
    const float* Ws_in  = (const float*)d_in[10];
    const float* bs_in  = (const float*)d_in[11];
    const float* Ws_out = (const float*)d_in[12];
    const float* bs_out = (const float*)d_in[13];

    const int total = 4 * HW4;            // 262144 float4-pair work items
    percnn_fused_kernel<<<total / 256, 256, 0, stream>>>(
        x, nu,
        Wc_in, bc_in, Wc_out, bc_out, Wd_in, bd_in, Wd_out, bd_out,
        Ws_in, bs_in, Ws_out, bs_out,
        (float*)d_out);
}